// Round 1
// baseline (667.899 us; speedup 1.0000x reference)
//
#include <hip/hip_runtime.h>
#include <math.h>

#define B 32
#define NQH 4
#define NKVH 2
#define HD 64
#define HIDDEN 256
#define QKV_DIM 512
#define MAX_SEQ 8192
#define Gq 2
#define CHUNK 1024
#define NCHUNK 8
#define PLANE (MAX_SEQ * HD)      // 524288 floats per (b,c,h) plane
#define SCALE 0.125f              // 1/sqrt(64)

// ws layout (floats):
//   q_rot   : [B][256]                      @ 0       (8192)
//   k_new   : [B][128]                      @ 8192    (4096)
//   v_new   : [B][128]                      @ 12288   (4096)
//   partials: [B*2][NCHUNK] x 132 floats    @ 16384   (512*132 = 67584)
//             entry: {m[2], l[2], acc[2][64]}
//   ctx     : [B][256]                      @ 83968   (8192)
#define WS_K    8192
#define WS_V    12288
#define WS_PART 16384
#define WS_CTX  83968

__global__ __launch_bounds__(256) void copy_kernel(const float4* __restrict__ src,
                                                   float4* __restrict__ dst, int n4) {
    int i = blockIdx.x * 256 + threadIdx.x;
    int stride = gridDim.x * 256;
    for (; i < n4; i += stride) dst[i] = src[i];
}

__global__ __launch_bounds__(256) void qkv_rope_kernel(
    const float* __restrict__ x, const int* __restrict__ ctx_len,
    const float* __restrict__ rope, const float* __restrict__ qkv_w,
    const float* __restrict__ qkv_b, float* __restrict__ out_kv,
    float* __restrict__ ws) {
    __shared__ float sx[HIDDEN];
    __shared__ float sqkv[QKV_DIM];
    int b = blockIdx.x, tid = threadIdx.x;
    sx[tid] = x[b * HIDDEN + tid];
    __syncthreads();
    const float4* sx4 = (const float4*)sx;
#pragma unroll
    for (int r = 0; r < 2; ++r) {
        int e = tid + r * 256;
        const float4* wrow = (const float4*)(qkv_w + e * HIDDEN);
        float acc = 0.f;
#pragma unroll 8
        for (int d4 = 0; d4 < HIDDEN / 4; ++d4) {
            float4 w = wrow[d4], xx = sx4[d4];
            acc += w.x * xx.x + w.y * xx.y + w.z * xx.z + w.w * xx.w;
        }
        sqkv[e] = acc + qkv_b[e];
    }
    __syncthreads();
    int pos = ctx_len[b];
    // RoPE on q (4 heads) and k (2 heads): 192 (d, half-pair) lanes
    if (tid < 192) {
        int which = tid >> 5;     // 0..3 q heads, 4..5 k heads
        int d = tid & 31;
        float c = rope[pos * HD + d];
        float s = rope[pos * HD + 32 + d];
        int base = (which < 4) ? which * HD : HIDDEN + (which - 4) * HD;
        float t1 = sqkv[base + d], t2 = sqkv[base + 32 + d];
        sqkv[base + d] = t1 * c - t2 * s;
        sqkv[base + 32 + d] = t1 * s + t2 * c;
    }
    __syncthreads();
    // q -> ws
    ws[b * HIDDEN + tid] = sqkv[tid];
    // k/v -> ws + scatter into out cache at row pos
    {
        float val = sqkv[256 + tid];
        if (tid < 128) {  // k
            int h = tid >> 6, d = tid & 63;
            ws[WS_K + b * 128 + tid] = val;
            out_kv[((size_t)(b * 2 + 0) * NKVH + h) * PLANE + (size_t)pos * HD + d] = val;
        } else {          // v
            int t = tid - 128;
            int h = t >> 6, d = t & 63;
            ws[WS_V + b * 128 + t] = val;
            out_kv[((size_t)(b * 2 + 1) * NKVH + h) * PLANE + (size_t)pos * HD + d] = val;
        }
    }
}

__global__ __launch_bounds__(256) void attn_kernel(
    const float* __restrict__ kv_cache, const int* __restrict__ ctx_len,
    const float* __restrict__ ws, float* __restrict__ partials) {
    int idx = blockIdx.x;
    int b = idx >> 4;
    int h = (idx >> 3) & 1;
    int chunk = idx & 7;
    int pos = ctx_len[b];
    int start = chunk * CHUNK;
    if (start >= pos) return;             // combine never reads these entries
    int end = min(start + CHUNK, pos);    // rows m < pos; row pos handled in combine
    int tid = threadIdx.x;
    int w = tid >> 6, lane = tid & 63;
    float q0 = ws[b * HIDDEN + (h * Gq + 0) * HD + lane];
    float q1 = ws[b * HIDDEN + (h * Gq + 1) * HD + lane];
    const float* kb = kv_cache + ((size_t)(b * 2 + 0) * NKVH + h) * PLANE;
    const float* vb = kv_cache + ((size_t)(b * 2 + 1) * NKVH + h) * PLANE;
    float mx0 = -INFINITY, mx1 = -INFINITY;
    float l0 = 0.f, l1 = 0.f, a0 = 0.f, a1 = 0.f;
    for (int m = start + w; m < end; m += 4) {
        float kvv = kb[(size_t)m * HD + lane];
        float vv = vb[(size_t)m * HD + lane];
        float s0 = q0 * kvv, s1 = q1 * kvv;
#pragma unroll
        for (int off = 32; off; off >>= 1) {
            s0 += __shfl_xor(s0, off);
            s1 += __shfl_xor(s1, off);
        }
        s0 *= SCALE; s1 *= SCALE;
        float nm0 = fmaxf(mx0, s0);
        float al0 = __expf(mx0 - nm0);
        float p0 = __expf(s0 - nm0);
        l0 = l0 * al0 + p0; a0 = a0 * al0 + p0 * vv; mx0 = nm0;
        float nm1 = fmaxf(mx1, s1);
        float al1 = __expf(mx1 - nm1);
        float p1 = __expf(s1 - nm1);
        l1 = l1 * al1 + p1; a1 = a1 * al1 + p1 * vv; mx1 = nm1;
    }
    __shared__ float sm[4][2], sl[4][2], sa[4][2][64];
    sa[w][0][lane] = a0;
    sa[w][1][lane] = a1;
    if (lane == 0) { sm[w][0] = mx0; sm[w][1] = mx1; sl[w][0] = l0; sl[w][1] = l1; }
    __syncthreads();
    if (tid < 128) {
        int g = tid >> 6, d = tid & 63;
        float M = fmaxf(fmaxf(sm[0][g], sm[1][g]), fmaxf(sm[2][g], sm[3][g]));
        float L = 0.f, A = 0.f;
#pragma unroll
        for (int ww = 0; ww < 4; ++ww) {
            float e = __expf(sm[ww][g] - M);
            L += sl[ww][g] * e;
            A += sa[ww][g][d] * e;
        }
        float* ent = partials + (size_t)((b * 2 + h) * NCHUNK + chunk) * 132;
        if (d == 0) { ent[g] = M; ent[2 + g] = L; }
        ent[4 + g * 64 + d] = A;
    }
}

__global__ __launch_bounds__(128) void combine_kernel(
    const int* __restrict__ ctx_len, const float* __restrict__ ws,
    float* __restrict__ ws_ctx) {
    int idx = blockIdx.x;  // b*2 + h
    int b = idx >> 1, h = idx & 1;
    int tid = threadIdx.x;
    int g = tid >> 6, d = tid & 63;
    int pos = ctx_len[b];
    float qv = ws[b * HIDDEN + (h * Gq + g) * HD + d];
    float kn = ws[WS_K + b * 128 + h * HD + d];
    float vn = ws[WS_V + b * 128 + h * HD + d];
    float s = qv * kn;
#pragma unroll
    for (int off = 32; off; off >>= 1) s += __shfl_xor(s, off);
    s *= SCALE;
    int nch = (pos + CHUNK - 1) >> 10;  // chunks containing rows m < pos
    const float* pbase = ws + WS_PART + (size_t)(b * 2 + h) * NCHUNK * 132;
    float M = s;
    for (int c = 0; c < nch; ++c) M = fmaxf(M, pbase[c * 132 + g]);
    float e0 = __expf(s - M);
    float L = e0;
    float A = e0 * vn;
    for (int c = 0; c < nch; ++c) {
        const float* ent = pbase + c * 132;
        float e = __expf(ent[g] - M);
        L += ent[2 + g] * e;
        A += ent[4 + g * 64 + d] * e;
    }
    ws_ctx[b * HIDDEN + (h * Gq + g) * HD + d] = A / L;
}

__global__ __launch_bounds__(256) void proj_kernel(
    const float* __restrict__ ws_ctx, const float* __restrict__ out_w,
    float* __restrict__ out) {
    __shared__ float sc[HIDDEN];
    int b = blockIdx.x, tid = threadIdx.x;
    sc[tid] = ws_ctx[b * HIDDEN + tid];
    __syncthreads();
    const float4* wrow = (const float4*)(out_w + tid * HIDDEN);
    const float4* s4 = (const float4*)sc;
    float acc = 0.f;
#pragma unroll 8
    for (int d4 = 0; d4 < HIDDEN / 4; ++d4) {
        float4 w = wrow[d4], xx = s4[d4];
        acc += w.x * xx.x + w.y * xx.y + w.z * xx.z + w.w * xx.w;
    }
    out[b * HIDDEN + tid] = acc;
}

extern "C" void kernel_launch(void* const* d_in, const int* in_sizes, int n_in,
                              void* d_out, int out_size, void* d_ws, size_t ws_size,
                              hipStream_t stream) {
    const float* x = (const float*)d_in[0];
    const float* kv = (const float*)d_in[1];
    const int* cl = (const int*)d_in[2];
    const float* rope = (const float*)d_in[3];
    const float* qw = (const float*)d_in[4];
    const float* qb = (const float*)d_in[5];
    const float* ow = (const float*)d_in[6];
    float* out = (float*)d_out;
    float* out_kv = out + B * HIDDEN;  // updated_kv starts after (B,1,256) out
    float* ws = (float*)d_ws;

    const int n4 = (B * 2 * NKVH * MAX_SEQ * HD) / 4;  // 16,777,216 float4
    copy_kernel<<<2048, 256, 0, stream>>>((const float4*)kv, (float4*)out_kv, n4);
    qkv_rope_kernel<<<B, 256, 0, stream>>>(x, cl, rope, qw, qb, out_kv, ws);
    attn_kernel<<<B * NKVH * NCHUNK, 256, 0, stream>>>(kv, cl, ws, ws + WS_PART);
    combine_kernel<<<B * NKVH, 128, 0, stream>>>(cl, ws, ws + WS_CTX);
    proj_kernel<<<B, 256, 0, stream>>>(ws + WS_CTX, ow, out);
}

// Round 2
// 501.688 us; speedup vs baseline: 1.3313x; 1.3313x over previous
//
#include <hip/hip_runtime.h>
#include <math.h>

#define B 32
#define NQH 4
#define NKVH 2
#define HD 64
#define HIDDEN 256
#define QKV_DIM 512
#define MAX_SEQ 8192
#define PLANE (MAX_SEQ * HD)      // 524288 floats per (b,c,h) plane
#define SCALE 0.125f              // 1/sqrt(64)
#define CH 256                    // rows per chunk-block
#define NCH (MAX_SEQ / CH)        // 32 chunks per (b,h)
#define NEG_BIG -1e30f

// ws layout (floats):
//   q_rot   : [B][256]                    @ 0       (8192)
//   k_new   : [B][128]                    @ 8192    (4096)
//   v_new   : [B][128]                    @ 12288   (4096)
//   partials: [B*2][NCH] x 132 floats     @ 16384   (64*32*132 = 270336)
//             entry: {m[2], l[2], acc[2][64]}
//   ctx     : [B][256]                    @ 286720  (8192)
#define WS_K    8192
#define WS_V    12288
#define WS_PART 16384
#define WS_CTX  286720

__global__ __launch_bounds__(256) void qkv_rope_kernel(
    const float* __restrict__ x, const int* __restrict__ ctx_len,
    const float* __restrict__ rope, const float* __restrict__ qkv_w,
    const float* __restrict__ qkv_b, float* __restrict__ ws) {
    __shared__ float sx[HIDDEN];
    __shared__ float sqkv[QKV_DIM];
    int b = blockIdx.x, tid = threadIdx.x;
    sx[tid] = x[b * HIDDEN + tid];
    __syncthreads();
    const float4* sx4 = (const float4*)sx;
#pragma unroll
    for (int r = 0; r < 2; ++r) {
        int e = tid + r * 256;
        const float4* wrow = (const float4*)(qkv_w + e * HIDDEN);
        float acc = 0.f;
#pragma unroll 8
        for (int d4 = 0; d4 < HIDDEN / 4; ++d4) {
            float4 w = wrow[d4], xx = sx4[d4];
            acc += w.x * xx.x + w.y * xx.y + w.z * xx.z + w.w * xx.w;
        }
        sqkv[e] = acc + qkv_b[e];
    }
    __syncthreads();
    int pos = ctx_len[b];
    if (tid < 192) {  // RoPE: 6 heads (4 q + 2 k) x 32 half-dims
        int which = tid >> 5;
        int d = tid & 31;
        float c = rope[pos * HD + d];
        float s = rope[pos * HD + 32 + d];
        int base = (which < 4) ? which * HD : HIDDEN + (which - 4) * HD;
        float t1 = sqkv[base + d], t2 = sqkv[base + 32 + d];
        sqkv[base + d] = t1 * c - t2 * s;
        sqkv[base + 32 + d] = t1 * s + t2 * c;
    }
    __syncthreads();
    ws[b * HIDDEN + tid] = sqkv[tid];                 // q
    if (tid < 128) ws[WS_K + b * 128 + tid] = sqkv[256 + tid];       // k
    else           ws[WS_V + b * 128 + (tid - 128)] = sqkv[384 + (tid - 128)]; // v
}

// One block per (b, h, 256-row chunk): copies the K and V chunk from the
// input cache to the output cache, and computes the online-softmax partial
// for rows < pos from the same registers. Wave layout: 4 row-groups of
// 16 lanes; lane j holds float4 j of the row (16B coalesced).
__global__ __launch_bounds__(256) void fused_copy_attn(
    const float* __restrict__ kv_cache, const int* __restrict__ ctx_len,
    const float* __restrict__ ws, float* __restrict__ out_kv,
    float* __restrict__ partials) {
    int idx = blockIdx.x;
    int chunk = idx & (NCH - 1);
    int h = (idx >> 5) & 1;
    int b = idx >> 6;
    int pos = ctx_len[b];
    int start = chunk * CH;
    int tid = threadIdx.x;
    int w = tid >> 6, lane = tid & 63;
    int g = lane >> 4, j = lane & 15;
    size_t koff = ((size_t)(b * 2 + 0) * NKVH + h) * PLANE;
    size_t voff = ((size_t)(b * 2 + 1) * NKVH + h) * PLANE;
    const float4* kin = (const float4*)(kv_cache + koff);
    const float4* vin = (const float4*)(kv_cache + voff);
    float4* kout = (float4*)(out_kv + koff);
    float4* vout = (float4*)(out_kv + voff);
    float4 q0 = *(const float4*)(ws + b * HIDDEN + (h * 2 + 0) * HD + 4 * j);
    float4 q1 = *(const float4*)(ws + b * HIDDEN + (h * 2 + 1) * HD + 4 * j);
    float m0 = NEG_BIG, m1 = NEG_BIG, l0 = 0.f, l1 = 0.f;
    float4 a0 = {0, 0, 0, 0}, a1 = {0, 0, 0, 0};
#pragma unroll 4
    for (int i = 0; i < CH / 16; ++i) {
        int row = start + i * 16 + w * 4 + g;
        int fidx = row * 16 + j;
        float4 k4 = kin[fidx];
        float4 v4 = vin[fidx];
        kout[fidx] = k4;
        vout[fidx] = v4;
        if (row < pos) {
            float s0 = q0.x * k4.x + q0.y * k4.y + q0.z * k4.z + q0.w * k4.w;
            float s1 = q1.x * k4.x + q1.y * k4.y + q1.z * k4.z + q1.w * k4.w;
#pragma unroll
            for (int off = 1; off <= 8; off <<= 1) {
                s0 += __shfl_xor(s0, off);
                s1 += __shfl_xor(s1, off);
            }
            s0 *= SCALE; s1 *= SCALE;
            float nm0 = fmaxf(m0, s0);
            float al0 = __expf(m0 - nm0);
            float p0 = __expf(s0 - nm0);
            l0 = l0 * al0 + p0;
            a0.x = a0.x * al0 + p0 * v4.x; a0.y = a0.y * al0 + p0 * v4.y;
            a0.z = a0.z * al0 + p0 * v4.z; a0.w = a0.w * al0 + p0 * v4.w;
            m0 = nm0;
            float nm1 = fmaxf(m1, s1);
            float al1 = __expf(m1 - nm1);
            float p1 = __expf(s1 - nm1);
            l1 = l1 * al1 + p1;
            a1.x = a1.x * al1 + p1 * v4.x; a1.y = a1.y * al1 + p1 * v4.y;
            a1.z = a1.z * al1 + p1 * v4.z; a1.w = a1.w * al1 + p1 * v4.w;
            m1 = nm1;
        }
    }
    if (start >= pos) return;   // pure-copy block: no partial entry
    // merge the 4 row-groups within the wave (xor 16, then 32)
#pragma unroll
    for (int off = 16; off <= 32; off <<= 1) {
        float om0 = __shfl_xor(m0, off), ol0 = __shfl_xor(l0, off);
        float om1 = __shfl_xor(m1, off), ol1 = __shfl_xor(l1, off);
        float4 oa0, oa1;
        oa0.x = __shfl_xor(a0.x, off); oa0.y = __shfl_xor(a0.y, off);
        oa0.z = __shfl_xor(a0.z, off); oa0.w = __shfl_xor(a0.w, off);
        oa1.x = __shfl_xor(a1.x, off); oa1.y = __shfl_xor(a1.y, off);
        oa1.z = __shfl_xor(a1.z, off); oa1.w = __shfl_xor(a1.w, off);
        float M0 = fmaxf(m0, om0);
        float ea0 = __expf(m0 - M0), eb0 = __expf(om0 - M0);
        l0 = l0 * ea0 + ol0 * eb0;
        a0.x = a0.x * ea0 + oa0.x * eb0; a0.y = a0.y * ea0 + oa0.y * eb0;
        a0.z = a0.z * ea0 + oa0.z * eb0; a0.w = a0.w * ea0 + oa0.w * eb0;
        m0 = M0;
        float M1 = fmaxf(m1, om1);
        float ea1 = __expf(m1 - M1), eb1 = __expf(om1 - M1);
        l1 = l1 * ea1 + ol1 * eb1;
        a1.x = a1.x * ea1 + oa1.x * eb1; a1.y = a1.y * ea1 + oa1.y * eb1;
        a1.z = a1.z * ea1 + oa1.z * eb1; a1.w = a1.w * ea1 + oa1.w * eb1;
        m1 = M1;
    }
    __shared__ float sm[4][2], sl[4][2], sacc[4][2][64];
    if (lane < 16) {
        *(float4*)&sacc[w][0][4 * j] = a0;
        *(float4*)&sacc[w][1][4 * j] = a1;
        if (j == 0) { sm[w][0] = m0; sm[w][1] = m1; sl[w][0] = l0; sl[w][1] = l1; }
    }
    __syncthreads();
    if (tid < 128) {
        int gg = tid >> 6, d = tid & 63;
        float M = fmaxf(fmaxf(sm[0][gg], sm[1][gg]), fmaxf(sm[2][gg], sm[3][gg]));
        float L = 0.f, A = 0.f;
#pragma unroll
        for (int ww = 0; ww < 4; ++ww) {
            float e = __expf(sm[ww][gg] - M);
            L += sl[ww][gg] * e;
            A += sacc[ww][gg][d] * e;
        }
        float* ent = partials + (size_t)((b * 2 + h) * NCH + chunk) * 132;
        if (d == 0) { ent[gg] = M; ent[2 + gg] = L; }
        ent[4 + gg * 64 + d] = A;
    }
}

__global__ __launch_bounds__(128) void combine_kernel(
    const int* __restrict__ ctx_len, const float* __restrict__ ws,
    float* __restrict__ out_kv, float* __restrict__ ws_ctx) {
    int idx = blockIdx.x;  // b*2 + h
    int b = idx >> 1, h = idx & 1;
    int tid = threadIdx.x;
    int g = tid >> 6, d = tid & 63;
    int pos = ctx_len[b];
    // scatter the new-token k/v row into the output cache (after copy)
    {
        float nv = ws[(g ? WS_V : WS_K) + b * 128 + h * HD + d];
        out_kv[((size_t)(b * 2 + g) * NKVH + h) * PLANE + (size_t)pos * HD + d] = nv;
    }
    float qv = ws[b * HIDDEN + (h * 2 + g) * HD + d];
    float kn = ws[WS_K + b * 128 + h * HD + d];
    float vn = ws[WS_V + b * 128 + h * HD + d];
    float s = qv * kn;
#pragma unroll
    for (int off = 32; off; off >>= 1) s += __shfl_xor(s, off);
    s *= SCALE;
    int nch = (pos + CH - 1) / CH;
    const float* pbase = ws + WS_PART + (size_t)(b * 2 + h) * NCH * 132;
    float M = s;
    for (int c = 0; c < nch; ++c) M = fmaxf(M, pbase[c * 132 + g]);
    float e0 = __expf(s - M);
    float L = e0;
    float A = e0 * vn;
    for (int c = 0; c < nch; ++c) {
        const float* ent = pbase + c * 132;
        float e = __expf(ent[g] - M);
        L += ent[2 + g] * e;
        A += ent[4 + g * 64 + d] * e;
    }
    ws_ctx[b * HIDDEN + (h * 2 + g) * HD + d] = A / L;
}

__global__ __launch_bounds__(256) void proj_kernel(
    const float* __restrict__ ws_ctx, const float* __restrict__ out_w,
    float* __restrict__ out) {
    __shared__ float sc[HIDDEN];
    int b = blockIdx.x, tid = threadIdx.x;
    sc[tid] = ws_ctx[b * HIDDEN + tid];
    __syncthreads();
    const float4* wrow = (const float4*)(out_w + tid * HIDDEN);
    const float4* s4 = (const float4*)sc;
    float acc = 0.f;
#pragma unroll 8
    for (int d4 = 0; d4 < HIDDEN / 4; ++d4) {
        float4 w = wrow[d4], xx = s4[d4];
        acc += w.x * xx.x + w.y * xx.y + w.z * xx.z + w.w * xx.w;
    }
    out[b * HIDDEN + tid] = acc;
}

extern "C" void kernel_launch(void* const* d_in, const int* in_sizes, int n_in,
                              void* d_out, int out_size, void* d_ws, size_t ws_size,
                              hipStream_t stream) {
    const float* x = (const float*)d_in[0];
    const float* kv = (const float*)d_in[1];
    const int* cl = (const int*)d_in[2];
    const float* rope = (const float*)d_in[3];
    const float* qw = (const float*)d_in[4];
    const float* qb = (const float*)d_in[5];
    const float* ow = (const float*)d_in[6];
    float* out = (float*)d_out;
    float* out_kv = out + B * HIDDEN;
    float* ws = (float*)d_ws;

    qkv_rope_kernel<<<B, 256, 0, stream>>>(x, cl, rope, qw, qb, ws);
    fused_copy_attn<<<B * NKVH * NCH, 256, 0, stream>>>(kv, cl, ws, out_kv, ws + WS_PART);
    combine_kernel<<<B * NKVH, 128, 0, stream>>>(cl, ws, out_kv, ws + WS_CTX);
    proj_kernel<<<B, 256, 0, stream>>>(ws + WS_CTX, ow, out);
}